// Round 8
// baseline (547.497 us; speedup 1.0000x reference)
//
#include <hip/hip_runtime.h>

typedef unsigned short u16;
typedef unsigned int   u32;

__device__ __forceinline__ float bf2f(u16 v) {
    return __uint_as_float(((u32)v) << 16);
}
__device__ __forceinline__ u16 f2bf(float f) {
    u32 u = __float_as_uint(f);
    u32 r = (u + 0x7fffu + ((u >> 16) & 1u)) >> 16;   // RNE
    return (u16)r;
}

#define LDP 132   // padded LDS row stride (floats); 132%32=4 -> conflict-free/2-way

// ---------------------------------------------------------------------------
// node_h: h = x @ W^T (bf16 out), fused al/ar (fp32, from fp32 accs).
// 256 thr, tile = 128 nodes x 128 cols, per-thread 8x8 register tile.
// x and W both staged in LDS (W in original [c][k] layout -> no transpose).
// LDS reads are b128; x-reads hit banks {0,4,8,12} (free), w-reads 2-way (free).
// ---------------------------------------------------------------------------
__global__ __launch_bounds__(256, 1) void node_h(
        const float* __restrict__ x, const float* __restrict__ W,
        const float* __restrict__ att,
        u16* __restrict__ hb, float* __restrict__ al, float* __restrict__ ar,
        int n) {
    __shared__ float xs[128 * LDP];    // 67.6 KB
    __shared__ float wsm[128 * LDP];   // 67.6 KB
    const int t  = threadIdx.x;
    const int nb = blockIdx.x * 128;

    const float4* W4 = (const float4*)W;
    const float4* x4 = (const float4*)x;
#pragma unroll
    for (int it = 0; it < 16; ++it) {
        int g = t + it * 256;          // float4 index
        int c = g >> 5, k4 = g & 31;
        *(float4*)&wsm[c * LDP + k4 * 4] = W4[g];
    }
#pragma unroll
    for (int it = 0; it < 16; ++it) {
        int g = t + it * 256;
        int r = g >> 5, k4 = g & 31;
        int node = nb + r;
        if (node >= n) node = n - 1;   // clamp (writes are guarded)
        *(float4*)&xs[r * LDP + k4 * 4] = x4[(size_t)node * 32 + k4];
    }
    __syncthreads();

    const int tc = t & 15;             // col  = tc + 16*j
    const int tn = t >> 4;             // node = tn + 16*i

    float acc[8][8];
#pragma unroll
    for (int i = 0; i < 8; ++i)
#pragma unroll
        for (int j = 0; j < 8; ++j) acc[i][j] = 0.f;

    for (int k0 = 0; k0 < 128; k0 += 4) {
        float4 xv[8], wv[8];
#pragma unroll
        for (int i = 0; i < 8; ++i)
            xv[i] = *(const float4*)&xs[(tn + 16 * i) * LDP + k0];
#pragma unroll
        for (int j = 0; j < 8; ++j)
            wv[j] = *(const float4*)&wsm[(tc + 16 * j) * LDP + k0];
#pragma unroll
        for (int i = 0; i < 8; ++i)
#pragma unroll
            for (int j = 0; j < 8; ++j) {
                acc[i][j] = fmaf(xv[i].x, wv[j].x, acc[i][j]);
                acc[i][j] = fmaf(xv[i].y, wv[j].y, acc[i][j]);
                acc[i][j] = fmaf(xv[i].z, wv[j].z, acc[i][j]);
                acc[i][j] = fmaf(xv[i].w, wv[j].w, acc[i][j]);
            }
    }

    // h store (bf16). cols tc+16j, nodes tn+16i.
#pragma unroll
    for (int i = 0; i < 8; ++i) {
        int node = nb + tn + 16 * i;
        if (node < n) {
#pragma unroll
            for (int j = 0; j < 8; ++j)
                hb[(size_t)node * 128 + tc + 16 * j] = f2bf(acc[i][j]);
        }
    }

    // al/ar: head == j (since col = tc + 16j, d = tc). Reduce over the 16
    // lanes (tc) of each node group via xor-shuffles (stay within 16 lanes).
    float attl[8], attr[8];
#pragma unroll
    for (int j = 0; j < 8; ++j) {
        attl[j] = att[j * 32 + tc];
        attr[j] = att[j * 32 + 16 + tc];
    }
#pragma unroll
    for (int i = 0; i < 8; ++i) {
        int node = nb + tn + 16 * i;
#pragma unroll
        for (int j = 0; j < 8; ++j) {
            float pl = acc[i][j] * attl[j];
            float pr = acc[i][j] * attr[j];
#pragma unroll
            for (int off = 1; off < 16; off <<= 1) {
                pl += __shfl_xor(pl, off, 64);
                pr += __shfl_xor(pr, off, 64);
            }
            if (tc == 0 && node < n) {
                al[node * 8 + j] = pl;
                ar[node * 8 + j] = pr;
            }
        }
    }
}

// ---- degree histogram -----------------------------------------------------
__global__ __launch_bounds__(256) void edge_hist(
        const int* __restrict__ ei, int* __restrict__ deg, int E) {
    int e = blockIdx.x * 256 + threadIdx.x;
    if (e < E) atomicAdd(&deg[ei[e]], 1);
}

// ---- exclusive scan, 1024 elems/block -------------------------------------
__global__ __launch_bounds__(256) void scan_blocks(
        const int* __restrict__ deg, int* __restrict__ rowstart,
        int* __restrict__ bsum, int n) {
    __shared__ int s[256];
    int t = threadIdx.x;
    int base = blockIdx.x * 1024 + t * 4;
    int v0 = (base + 0 < n) ? deg[base + 0] : 0;
    int v1 = (base + 1 < n) ? deg[base + 1] : 0;
    int v2 = (base + 2 < n) ? deg[base + 2] : 0;
    int v3 = (base + 3 < n) ? deg[base + 3] : 0;
    int sum = v0 + v1 + v2 + v3;
    s[t] = sum;
    __syncthreads();
    for (int off = 1; off < 256; off <<= 1) {
        int tmp = (t >= off) ? s[t - off] : 0;
        __syncthreads();
        s[t] += tmp;
        __syncthreads();
    }
    int excl = s[t] - sum;
    if (base + 0 < n) rowstart[base + 0] = excl;
    if (base + 1 < n) rowstart[base + 1] = excl + v0;
    if (base + 2 < n) rowstart[base + 2] = excl + v0 + v1;
    if (base + 3 < n) rowstart[base + 3] = excl + v0 + v1 + v2;
    if (t == 255) bsum[blockIdx.x] = s[255];
}

__global__ __launch_bounds__(256) void scan_top(int* __restrict__ bsum, int nb) {
    __shared__ int s[256];
    int t = threadIdx.x;
    int v = (t < nb) ? bsum[t] : 0;
    s[t] = v;
    __syncthreads();
    for (int off = 1; off < 256; off <<= 1) {
        int tmp = (t >= off) ? s[t - off] : 0;
        __syncthreads();
        s[t] += tmp;
        __syncthreads();
    }
    if (t < nb) bsum[t] = s[t] - v;               // exclusive
}

__global__ __launch_bounds__(256) void scan_add(
        int* __restrict__ rowstart, int* __restrict__ cursor,
        const int* __restrict__ bsum, int n) {
    int i = blockIdx.x * 256 + threadIdx.x;
    if (i < n) {
        int v = rowstart[i] + bsum[i >> 10];
        rowstart[i] = v;
        cursor[i]   = v;
    }
}

// ---- fill CSR col list (cursor ends at row end) ---------------------------
__global__ __launch_bounds__(256) void edge_fill(
        const int* __restrict__ ei, int* __restrict__ cursor,
        int* __restrict__ csr, int E) {
    int e = blockIdx.x * 256 + threadIdx.x;
    if (e >= E) return;
    int r = ei[e];
    int c = ei[E + e];
    int p = atomicAdd(&cursor[r], 1);
    csr[p] = c;
}

// ---- wave per row, 2 edges/iter, bf16 h gather ----------------------------
// lanes 0-31: edge j (lane l -> cols 4l..4l+3, ushort4); lanes 32-63: edge j+1.
__global__ __launch_bounds__(256) void row_gather(
        const int* __restrict__ csr, const int* __restrict__ rowstart,
        const int* __restrict__ rowend,
        const float* __restrict__ pos, const float* __restrict__ al,
        const float* __restrict__ ar, const u16* __restrict__ hb,
        float* __restrict__ out, int n) {
    int r    = (blockIdx.x * 256 + threadIdx.x) >> 6;
    int lane = threadIdx.x & 63;
    if (r >= n) return;
    int s = rowstart[r];
    int e = rowend[r];
    if (s >= e) {                       // empty row -> zeros
        if (lane < 32) *(float4*)&out[(size_t)r * 128 + lane * 4] =
            make_float4(0.f, 0.f, 0.f, 0.f);
        return;
    }
    const int sub  = lane >> 5;
    const int l31  = lane & 31;
    const int head = l31 >> 2;
    float al_l = (l31 < 8) ? al[r * 8 + l31] : 0.f;
    float4 acc = make_float4(0.f, 0.f, 0.f, 0.f);
    float rs = 0.f;
#pragma unroll 2
    for (int j = s; j < e; j += 2) {
        int  jj    = j + sub;
        bool valid = (jj < e);
        int  c     = csr[valid ? jj : s];
        float av = 0.f;
        if (l31 < 8 && valid) {
            float a = al_l + ar[c * 8 + l31];
            a  = (a >= 0.f) ? a : 0.2f * a;
            av = __expf(a) * pos[c];
            rs += av;
        }
        float alpha = __shfl(av, (lane & 32) + head, 64);
        ushort4 hv = *(const ushort4*)&hb[(size_t)c * 128 + l31 * 4];
        acc.x = fmaf(alpha, bf2f(hv.x), acc.x);
        acc.y = fmaf(alpha, bf2f(hv.y), acc.y);
        acc.z = fmaf(alpha, bf2f(hv.z), acc.z);
        acc.w = fmaf(alpha, bf2f(hv.w), acc.w);
    }
    rs    += __shfl_xor(rs, 32, 64);
    acc.x += __shfl_xor(acc.x, 32, 64);
    acc.y += __shfl_xor(acc.y, 32, 64);
    acc.z += __shfl_xor(acc.z, 32, 64);
    acc.w += __shfl_xor(acc.w, 32, 64);
    float rsh = __shfl(rs, head, 64);
    float sc = (rsh != 0.f) ? (1.f / rsh + 1e-16f) : 0.f;
    if (lane < 32) {
        float4 o = make_float4(acc.x * sc, acc.y * sc, acc.z * sc, acc.w * sc);
        *(float4*)&out[(size_t)r * 128 + lane * 4] = o;
    }
}

extern "C" void kernel_launch(void* const* d_in, const int* in_sizes, int n_in,
                              void* d_out, int out_size, void* d_ws, size_t ws_size,
                              hipStream_t stream) {
    // identify inputs by unique sizes (robust to ordering)
    const float* x   = nullptr;
    const int*   ei  = nullptr;
    const float* pos = nullptr;
    const float* W   = nullptr;
    const float* att = nullptr;
    int E2 = 0;
    for (int i = 0; i < n_in; ++i) {
        int s = in_sizes[i];
        if      (s == out_size)        x   = (const float*)d_in[i];
        else if (s == out_size / 128)  pos = (const float*)d_in[i];
        else if (s == 16384)           W   = (const float*)d_in[i];
        else if (s == 256)             att = (const float*)d_in[i];
        else { ei = (const int*)d_in[i]; E2 = s; }
    }
    float* out = (float*)d_out;
    const int N_ = out_size / 128;     // 100000
    const int E_ = E2 / 2;             // 1600000

    // workspace: hb (u16 N*128) | al | ar (fp32) | deg | rowstart | cursor |
    //            bsum | csr
    u16*   hb = (u16*)d_ws;
    float* al = (float*)(hb + (size_t)N_ * 128);
    float* ar = al + (size_t)N_ * 8;
    int* deg      = (int*)(ar + (size_t)N_ * 8);
    int* rowstart = deg + N_;
    int* cursor   = rowstart + N_;
    int* bsum     = cursor + N_;
    int* csr      = bsum + 256;

    const int nb_scan = (N_ + 1023) / 1024;      // <=256

    hipMemsetAsync(deg, 0, (size_t)N_ * sizeof(int), stream);

    node_h<<<(N_ + 127) / 128, 256, 0, stream>>>(x, W, att, hb, al, ar, N_);
    edge_hist<<<(E_ + 255) / 256, 256, 0, stream>>>(ei, deg, E_);
    scan_blocks<<<nb_scan, 256, 0, stream>>>(deg, rowstart, bsum, N_);
    scan_top<<<1, 256, 0, stream>>>(bsum, nb_scan);
    scan_add<<<(N_ + 255) / 256, 256, 0, stream>>>(rowstart, cursor, bsum, N_);
    edge_fill<<<(E_ + 255) / 256, 256, 0, stream>>>(ei, cursor, csr, E_);
    row_gather<<<(N_ * 64 + 255) / 256, 256, 0, stream>>>(
        csr, rowstart, cursor, pos, al, ar, hb, out, N_);
}